// Round 20
// baseline (769.111 us; speedup 1.0000x reference)
//
#include <hip/hip_runtime.h>
#include <stdint.h>

#define N_ATOMS   100000
#define N_BONDS   200000
#define N_MOLS    4000
#define MAX_NB    6
#define ATOM_FDIM 133
#define BOND_FDIM 14
#define HIDDEN    300
#define NPAD      320

typedef __attribute__((ext_vector_type(8))) short          bf16x8;
typedef __attribute__((ext_vector_type(8))) unsigned short u16x8;
typedef __attribute__((ext_vector_type(4))) float          f32x4;
typedef __attribute__((ext_vector_type(4))) unsigned int   u32x4;

static __device__ __forceinline__ float u2f(unsigned int u) {
  union { unsigned int u; float f; } v; v.u = u; return v.f;
}
static __device__ __forceinline__ unsigned int f2u(float f) {
  union { float f; unsigned int u; } v; v.f = f; return v.u;
}
static __device__ __forceinline__ float bflo(unsigned int u) { return u2f(u << 16); }
static __device__ __forceinline__ float bfhi(unsigned int u) { return u2f(u & 0xffff0000u); }
static __device__ __forceinline__ unsigned short f2bf_rn(float f) {
  unsigned int u = f2u(f);
  return (unsigned short)((u + 0x7fffu + ((u >> 16) & 1u)) >> 16);
}
static __device__ __forceinline__ unsigned int pack_rn(float lo, float hi) {
  return ((unsigned int)f2bf_rn(hi) << 16) | f2bf_rn(lo);
}

// ---- input pad/convert: f32[N][K] -> bf16[N][KP], zero pad ----
__global__ __launch_bounds__(256) void convin_kernel(
    const float* __restrict__ w, unsigned short* __restrict__ o, int N, int K, int KP) {
  size_t total = (size_t)N * KP;
  for (size_t idx = (size_t)blockIdx.x * 256 + threadIdx.x; idx < total; idx += (size_t)gridDim.x * 256) {
    int n = (int)(idx / KP), k = (int)(idx - (size_t)n * KP);
    float v = (k < K) ? w[(size_t)n * K + k] : 0.f;
    o[idx] = f2bf_rn(v);
  }
}

// ---- weight pad/convert, generic 2-segment remap: o[NPAD][KP] bf16 ----
__global__ __launch_bounds__(256) void convw_kernel(
    const float* __restrict__ w, unsigned short* __restrict__ o,
    int Ksrc, int seg1, int src2off, int seg2dst, int seg2len, int KP) {
  int total = NPAD * KP;
  for (int idx = blockIdx.x * 256 + threadIdx.x; idx < total; idx += gridDim.x * 256) {
    int n = idx / KP, k = idx - n * KP;
    int src = -1;
    if (k < seg1) src = k;
    else if (k >= seg2dst && k < seg2dst + seg2len) src = src2off + (k - seg2dst);
    float v = (n < HIDDEN && src >= 0) ? w[(size_t)n * Ksrc + src] : 0.f;
    o[idx] = f2bf_rn(v);
  }
}

// ---- tile-pipelined MFMA GEMM with global_load_lds staging ----
// r20: launch_bounds(256,2) (256-reg budget: proven spill-free for acc[4][5]
// kernels, prevents the unbounded 252-VGPR allocation) + B-prefetch removed
// (r10: neutral for perf, costs 40 VGPR).
template<int KP, int SEG, bool RELU>
__global__ __launch_bounds__(256, 2) void gemm_tp(
    const unsigned short* S1, const unsigned short* __restrict__ S2,
    const int* __restrict__ gmap, const unsigned short* __restrict__ W,
    unsigned short* out, int M, int nTiles) {
  constexpr int CHUNKS = KP / 8;
  constexpr int NST    = KP / 32;
  __shared__ __align__(16) unsigned short As[2 * 64 * KP];

  const int tid  = threadIdx.x;
  const int lane = tid & 63;
  const int wv   = tid >> 6;
  const int ar   = lane & 15, kq = lane >> 4;
  const int nbase = wv * 80;
  const unsigned short* Wl = W + (size_t)(nbase + ar) * KP + kq * 8;

  auto rowof = [&](int tile) { int r = tile * 64 + lane; return (r < M) ? r : (M - 1); };

  auto stage = [&](int buf, int drow, int srow) {
    char* base = (char*)As + (size_t)buf * (64 * KP * 2);
#pragma unroll
    for (int cs = wv; cs < CHUNKS; cs += 4) {
      const unsigned short* src;
      if (SEG == 0) src = S1 + (size_t)drow * KP + cs * 8;
      else src = (cs < 20) ? (S1 + (size_t)srow * 160 + cs * 8)
                           : (S2 + (size_t)drow * 32 + (cs - 20) * 8);
      __builtin_amdgcn_global_load_lds(
          (const __attribute__((address_space(1))) void*)src,
          (__attribute__((address_space(3))) void*)(base + (size_t)cs * 1024), 16, 0, 0);
    }
  };

  f32x4 acc[4][5];

  auto compute = [&](int buf) {
    const char* base = (const char*)As + (size_t)buf * (64 * KP * 2);
#pragma unroll
    for (int ks = 0; ks < NST; ks++) {
      bf16x8 af[4];
#pragma unroll
      for (int m = 0; m < 4; m++)
        af[m] = *(const bf16x8*)(base + (size_t)((ks * 4 + kq) * 64 + m * 16 + ar) * 16);
#pragma unroll
      for (int nf = 0; nf < 5; nf++) {
        bf16x8 bfr = *(const bf16x8*)(Wl + (size_t)nf * 16 * KP + ks * 32);
#pragma unroll
        for (int m = 0; m < 4; m++)
          acc[m][nf] = __builtin_amdgcn_mfma_f32_16x16x32_bf16(af[m], bfr, acc[m][nf], 0, 0, 0);
      }
    }
  };

  auto storeC = [&](int tile) {
#pragma unroll
    for (int m = 0; m < 4; m++)
#pragma unroll
      for (int rr = 0; rr < 4; rr++) {
        int orow = tile * 64 + m * 16 + kq * 4 + rr;
        if (orow >= M) continue;
#pragma unroll
        for (int nf = 0; nf < 5; nf++) {
          float v = acc[m][nf][rr];
          if (RELU) v = v > 0.f ? v : 0.f;
          out[(size_t)orow * NPAD + nbase + nf * 16 + ar] = f2bf_rn(v);
        }
      }
  };

  int t = blockIdx.x;
  if (t >= nTiles) return;
  {
    int srow0 = (SEG == 1) ? gmap[rowof(t)] : 0;
    stage(0, rowof(t), srow0);
  }
  int tn = t + gridDim.x;
  int g_n = (SEG == 1 && tn < nTiles) ? gmap[rowof(tn)] : 0;
  __syncthreads();

  int cur = 0;
  while (t < nTiles) {
    const int nxt = t + gridDim.x;
    if (nxt < nTiles) stage(cur ^ 1, rowof(nxt), g_n);
    const int t2 = nxt + gridDim.x;
    int g_n2 = (SEG == 1 && t2 < nTiles) ? gmap[rowof(t2)] : 0;
#pragma unroll
    for (int m = 0; m < 4; m++)
#pragma unroll
      for (int n = 0; n < 5; n++) acc[m][n] = (f32x4){0.f, 0.f, 0.f, 0.f};
    compute(cur);
    __syncthreads();
    storeC(t);
    cur ^= 1; t = nxt; g_n = g_n2;
  }
}

// ---- fused combine+GEMM, K-chunked unit pipeline (r18-proven) ----
__global__ __launch_bounds__(256) void gemm_tpf(
    const unsigned short* Z, const unsigned short* __restrict__ Nei,
    const int* __restrict__ b2a, const unsigned short* __restrict__ W,
    unsigned short* out, int nTiles) {
  constexpr int KP = 320, BK = 160, NCH = 2, NSTC = 5, NREG = 5;
  __shared__ __align__(16) unsigned short As[2 * 64 * BK];   // 40 KB

  const int tid  = threadIdx.x;
  const int lane = tid & 63;
  const int wv   = tid >> 6;
  const int ar   = lane & 15, kq = lane >> 4;
  const int nbase = wv * 80;
  const unsigned short* Wl = W + (size_t)(nbase + ar) * KP + kq * 8;

  u32x4 nei4[NREG], z4[NREG];

  auto loadreg = [&](int tile, int chunk) {
    const int row = tile * 64 + lane;          // N_BONDS is 64-aligned
    const int g   = b2a[row];
    const int rev = row ^ 1;
    const int kb  = chunk * BK;
#pragma unroll
    for (int i = 0; i < NREG; i++) {
      const int cs = i * 4 + wv;               // 0..19
      nei4[i] = *(const u32x4*)(Nei + (size_t)g * NPAD + kb + cs * 8);
      z4[i]   = *(const u32x4*)(Z + (size_t)rev * NPAD + kb + cs * 8);
    }
  };

  auto writestage = [&](int buf) {
    char* base = (char*)As + (size_t)buf * (64 * BK * 2);
#pragma unroll
    for (int i = 0; i < NREG; i++) {
      const int cs = i * 4 + wv;
      u32x4 o;
#pragma unroll
      for (int t4 = 0; t4 < 4; t4++) {
        float lo = bflo(nei4[i][t4]) - bflo(z4[i][t4]);
        float hi = bfhi(nei4[i][t4]) - bfhi(z4[i][t4]);
        lo = lo > 0.f ? lo : 0.f; hi = hi > 0.f ? hi : 0.f;
        o[t4] = pack_rn(lo, hi);
      }
      *(u32x4*)(base + (size_t)(cs * 64 + lane) * 16) = o;
    }
  };

  f32x4 acc[4][5];

  auto compute = [&](int buf, int chunk) {
    const char* base = (const char*)As + (size_t)buf * (64 * BK * 2);
    const int kb = chunk * BK;
#pragma unroll
    for (int ks = 0; ks < NSTC; ks++) {
      bf16x8 af[4];
#pragma unroll
      for (int m = 0; m < 4; m++)
        af[m] = *(const bf16x8*)(base + (size_t)((ks * 4 + kq) * 64 + m * 16 + ar) * 16);
#pragma unroll
      for (int nf = 0; nf < 5; nf++) {
        bf16x8 bfr = *(const bf16x8*)(Wl + (size_t)nf * 16 * KP + kb + ks * 32);
#pragma unroll
        for (int m = 0; m < 4; m++)
          acc[m][nf] = __builtin_amdgcn_mfma_f32_16x16x32_bf16(af[m], bfr, acc[m][nf], 0, 0, 0);
      }
    }
  };

  auto storeC = [&](int tile) {
#pragma unroll
    for (int m = 0; m < 4; m++)
#pragma unroll
      for (int rr = 0; rr < 4; rr++) {
        int orow = tile * 64 + m * 16 + kq * 4 + rr;
#pragma unroll
        for (int nf = 0; nf < 5; nf++)
          out[(size_t)orow * NPAD + nbase + nf * 16 + ar] = f2bf_rn(acc[m][nf][rr]);
      }
  };

  int t = blockIdx.x;
  if (t >= nTiles) return;
  loadreg(t, 0);
  writestage(0);
  __syncthreads();

  int cur = 0;
  while (t < nTiles) {
#pragma unroll
    for (int m = 0; m < 4; m++)
#pragma unroll
      for (int n = 0; n < 5; n++) acc[m][n] = (f32x4){0.f, 0.f, 0.f, 0.f};
#pragma unroll
    for (int c = 0; c < NCH; c++) {
      int nt = t, nc = c + 1;
      if (nc == NCH) { nt = t + gridDim.x; nc = 0; }
      const bool valid = nt < nTiles;
      if (valid) loadreg(nt, nc);       // issue early: hides under compute
      compute(cur, c);
      if (valid) writestage(cur ^ 1);   // waits loads; ds_write late
      __syncthreads();
      cur ^= 1;
    }
    storeC(t);
    t += gridDim.x;
  }
}

// ---- final KP=480 GEMM: K-chunked tile pipeline, reg-budget 256 (r20) ----
__global__ __launch_bounds__(256, 2) void gemm_tpo(
    const unsigned short* __restrict__ fa_bf, const unsigned short* Ab,
    const unsigned short* __restrict__ W, const float* __restrict__ bias,
    unsigned short* out, int M, int nTiles) {
  constexpr int KP = 480, BK = 160, NCH = 3, NSTC = 5, CHG = 20;
  __shared__ __align__(16) unsigned short As[2 * 64 * BK];   // 40 KB

  const int tid  = threadIdx.x;
  const int lane = tid & 63;
  const int wv   = tid >> 6;
  const int ar   = lane & 15, kq = lane >> 4;
  const int nbase = wv * 80;
  const unsigned short* Wl = W + (size_t)(nbase + ar) * KP + kq * 8;

  auto stage = [&](int buf, int tile, int chunk) {
    char* base = (char*)As + (size_t)buf * (64 * BK * 2);
    int r = tile * 64 + lane; if (r >= M) r = M - 1;
#pragma unroll
    for (int cl = wv; cl < CHG; cl += 4) {
      const int ae = (chunk * CHG + cl) * 8;
      const unsigned short* src = (ae < 160)
          ? (fa_bf + (size_t)r * 160 + ae)
          : (Ab + (size_t)r * NPAD + (ae - 160));
      __builtin_amdgcn_global_load_lds(
          (const __attribute__((address_space(1))) void*)src,
          (__attribute__((address_space(3))) void*)(base + (size_t)cl * 1024), 16, 0, 0);
    }
  };

  f32x4 acc[4][5];

  auto compute = [&](int buf, int chunk) {
    const char* base = (const char*)As + (size_t)buf * (64 * BK * 2);
    const int kb = chunk * BK;
#pragma unroll
    for (int ks = 0; ks < NSTC; ks++) {
      bf16x8 af[4];
#pragma unroll
      for (int m = 0; m < 4; m++)
        af[m] = *(const bf16x8*)(base + (size_t)((ks * 4 + kq) * 64 + m * 16 + ar) * 16);
#pragma unroll
      for (int nf = 0; nf < 5; nf++) {
        bf16x8 bfr = *(const bf16x8*)(Wl + (size_t)nf * 16 * KP + kb + ks * 32);
#pragma unroll
        for (int m = 0; m < 4; m++)
          acc[m][nf] = __builtin_amdgcn_mfma_f32_16x16x32_bf16(af[m], bfr, acc[m][nf], 0, 0, 0);
      }
    }
  };

  auto storeC = [&](int tile) {
#pragma unroll
    for (int m = 0; m < 4; m++)
#pragma unroll
      for (int rr = 0; rr < 4; rr++) {
        int orow = tile * 64 + m * 16 + kq * 4 + rr;
        if (orow >= M) continue;
#pragma unroll
        for (int nf = 0; nf < 5; nf++) {
          int ocol = nbase + nf * 16 + ar;
          float v = acc[m][nf][rr];
          v += (ocol < HIDDEN) ? bias[ocol] : 0.f;
          v = v > 0.f ? v : 0.f;
          out[(size_t)orow * NPAD + ocol] = f2bf_rn(v);
        }
      }
  };

  int t = blockIdx.x;
  if (t >= nTiles) return;
  stage(0, t, 0);
  __syncthreads();

  int cur = 0;
  while (t < nTiles) {
#pragma unroll
    for (int m = 0; m < 4; m++)
#pragma unroll
      for (int n = 0; n < 5; n++) acc[m][n] = (f32x4){0.f, 0.f, 0.f, 0.f};
#pragma unroll
    for (int c = 0; c < NCH; c++) {
      int nt = t, nc = c + 1;
      if (nc == NCH) { nt = t + gridDim.x; nc = 0; }
      if (nt < nTiles) stage(cur ^ 1, nt, nc);
      compute(cur, c);
      __syncthreads();
      cur ^= 1;
    }
    storeC(t);
    t += gridDim.x;
  }
}

// ---- neighbor aggregate: dst[a][:] = sum_j src[a2b[a][j]][:] ----
__global__ __launch_bounds__(256) void agg_kernel(
    const unsigned short* __restrict__ src, const int* __restrict__ a2b,
    unsigned short* __restrict__ dst) {
  const int TPA = NPAD / 16;  // 20
  int idx = blockIdx.x * 256 + threadIdx.x;
  if (idx >= N_ATOMS * TPA) return;
  int a  = idx / TPA;
  int kc = (idx - a * TPA) * 16;
  int bidx[MAX_NB];
#pragma unroll
  for (int j = 0; j < MAX_NB; j++) bidx[j] = a2b[a * MAX_NB + j];
  float slo[8], shi[8];
#pragma unroll
  for (int t = 0; t < 8; t++) { slo[t] = 0.f; shi[t] = 0.f; }
#pragma unroll
  for (int j = 0; j < MAX_NB; j++) {
    const u32x4* p = (const u32x4*)(src + (size_t)bidx[j] * NPAD + kc);
    u32x4 v0 = p[0], v1 = p[1];
#pragma unroll
    for (int t = 0; t < 4; t++) {
      slo[t]     += bflo(v0[t]); shi[t]     += bfhi(v0[t]);
      slo[4 + t] += bflo(v1[t]); shi[4 + t] += bfhi(v1[t]);
    }
  }
  u32x4 o0, o1;
#pragma unroll
  for (int t = 0; t < 4; t++) { o0[t] = pack_rn(slo[t], shi[t]); o1[t] = pack_rn(slo[4 + t], shi[4 + t]); }
  u32x4* qp = (u32x4*)(dst + (size_t)a * NPAD + kc);
  qp[0] = o0; qp[1] = o1;
}

// ---- pairwise: msg[b] = relu(neiZ[b2a[b]] - Zh[b^1]), in-place over Zh ----
__global__ __launch_bounds__(256) void combineH_kernel(
    const unsigned short* __restrict__ neiZ, const unsigned short* Zh,
    const int* __restrict__ b2a, unsigned short* msg) {
  const int TPB = NPAD / 16;  // 20
  const int NPAIR = N_BONDS / 2;
  int idx = blockIdx.x * 256 + threadIdx.x;
  if (idx >= NPAIR * TPB) return;
  int p  = idx / TPB;
  int kc = (idx - p * TPB) * 16;
  int b0i = 2 * p, b1i = 2 * p + 1;
  int g0 = b2a[b0i], g1 = b2a[b1i];
  const u32x4* pn0 = (const u32x4*)(neiZ + (size_t)g0 * NPAD + kc);
  const u32x4* pn1 = (const u32x4*)(neiZ + (size_t)g1 * NPAD + kc);
  const u32x4* pz0 = (const u32x4*)(Zh + (size_t)b1i * NPAD + kc);
  const u32x4* pz1 = (const u32x4*)(Zh + (size_t)b0i * NPAD + kc);
  u32x4 n00 = pn0[0], n01 = pn0[1], n10 = pn1[0], n11 = pn1[1];
  u32x4 z00 = pz0[0], z01 = pz0[1], z10 = pz1[0], z11 = pz1[1];
  u32x4 o00, o01, o10, o11;
#pragma unroll
  for (int t = 0; t < 4; t++) {
    float a, c;
    a = bflo(n00[t]) - bflo(z00[t]); c = bfhi(n00[t]) - bfhi(z00[t]);
    o00[t] = pack_rn(a > 0.f ? a : 0.f, c > 0.f ? c : 0.f);
    a = bflo(n01[t]) - bflo(z01[t]); c = bfhi(n01[t]) - bfhi(z01[t]);
    o01[t] = pack_rn(a > 0.f ? a : 0.f, c > 0.f ? c : 0.f);
    a = bflo(n10[t]) - bflo(z10[t]); c = bfhi(n10[t]) - bfhi(z10[t]);
    o10[t] = pack_rn(a > 0.f ? a : 0.f, c > 0.f ? c : 0.f);
    a = bflo(n11[t]) - bflo(z11[t]); c = bfhi(n11[t]) - bfhi(z11[t]);
    o11[t] = pack_rn(a > 0.f ? a : 0.f, c > 0.f ? c : 0.f);
  }
  u32x4* q0 = (u32x4*)(msg + (size_t)b0i * NPAD + kc);
  u32x4* q1 = (u32x4*)(msg + (size_t)b1i * NPAD + kc);
  q0[0] = o00; q0[1] = o01; q1[0] = o10; q1[1] = o11;
}

// ---- per-molecule mean readout ----
__global__ __launch_bounds__(256) void readout_kernel(
    const unsigned short* __restrict__ hidden, const int* __restrict__ a_scope,
    float* __restrict__ out) {
  const int TPM = NPAD / 8;  // 40
  int idx = blockIdx.x * 256 + threadIdx.x;
  if (idx >= N_MOLS * TPM) return;
  int m = idx / TPM;
  int c = (idx - m * TPM) * 8;
  int start = a_scope[m * 2], size = a_scope[m * 2 + 1];
  float s[8];
#pragma unroll
  for (int t = 0; t < 8; t++) s[t] = 0.f;
  for (int i = 0; i < size; i++) {
    const u32x4 v = *(const u32x4*)(hidden + (size_t)(start + i) * NPAD + c);
#pragma unroll
    for (int t = 0; t < 4; t++) { s[2 * t] += bflo(v[t]); s[2 * t + 1] += bfhi(v[t]); }
  }
  float inv = (size > 0) ? 1.f / (float)size : 0.f;
#pragma unroll
  for (int t = 0; t < 8; t++) {
    int col = c + t;
    if (col < HIDDEN) out[(size_t)m * HIDDEN + col] = s[t] * inv;
  }
}

extern "C" void kernel_launch(void* const* d_in, const int* in_sizes, int n_in,
                              void* d_out, int out_size, void* d_ws, size_t ws_size,
                              hipStream_t stream) {
  const float* f_atoms = (const float*)d_in[0];
  const float* f_bonds = (const float*)d_in[1];
  const int*   a2b     = (const int*)d_in[2];
  const int*   b2a     = (const int*)d_in[3];
  // d_in[4] = b2revb == b^1 (constant from setup), folded into combine paths
  const int*   a_scope = (const int*)d_in[5];
  const float* W_i     = (const float*)d_in[6];
  const float* W_h     = (const float*)d_in[7];
  const float* W_o     = (const float*)d_in[8];
  const float* b_o     = (const float*)d_in[9];
  float* out = (float*)d_out;

  // ---- workspace: P 128 + R 64 + fa_bf 32 + fb_bf 12.8 + W ~0.7 = 237.5 MB ----
  char* ws = (char*)d_ws;
  size_t off = 0;
  auto alloc = [&](size_t bytes) { size_t o = off; off += (bytes + 255) & ~(size_t)255; return o; };
  unsigned short* P     = (unsigned short*)(ws + alloc((size_t)N_BONDS * NPAD * 2)); // msg/Z
  unsigned short* R     = (unsigned short*)(ws + alloc((size_t)N_ATOMS * NPAD * 2)); // nei/amsg/hidden
  unsigned short* fa_bf = (unsigned short*)(ws + alloc((size_t)N_ATOMS * 160 * 2));
  unsigned short* fb_bf = (unsigned short*)(ws + alloc((size_t)N_BONDS * 32 * 2));
  unsigned short* WiAB  = (unsigned short*)(ws + alloc((size_t)NPAD * 192 * 2));
  unsigned short* Wh    = (unsigned short*)(ws + alloc((size_t)NPAD * 320 * 2));
  unsigned short* Wo    = (unsigned short*)(ws + alloc((size_t)NPAD * 480 * 2));

  convin_kernel<<<2048, 256, 0, stream>>>(f_atoms, fa_bf, N_ATOMS, ATOM_FDIM, 160);
  convin_kernel<<<2048, 256, 0, stream>>>(f_bonds, fb_bf, N_BONDS, BOND_FDIM, 32);
  convw_kernel<<<(NPAD * 192 + 255) / 256, 256, 0, stream>>>(W_i, WiAB, 147, 133, 133, 160, 14, 192);
  convw_kernel<<<(NPAD * 320 + 255) / 256, 256, 0, stream>>>(W_h, Wh, 300, 300, 0, 0, 0, 320);
  convw_kernel<<<(NPAD * 480 + 255) / 256, 256, 0, stream>>>(W_o, Wo, 433, 133, 133, 160, 300, 480);

  const int nTilesB = N_BONDS / 64;           // 3125
  const int nTilesA = (N_ATOMS + 63) / 64;    // 1563
  const int gagg = (N_ATOMS * (NPAD / 16) + 255) / 256;
  const int gpar = ((N_BONDS / 2) * (NPAD / 16) + 255) / 256;

  // 1) L1: P = msg0 = relu([fa_bf[b2a]|fb_bf] @ WiAB^T)
  gemm_tp<192, 1, true><<<768, 256, 0, stream>>>(
      fa_bf, fb_bf, b2a, WiAB, P, N_BONDS, nTilesB);

  // 2) Z1 = msg0 @ Wh^T (in-place P); nei1 -> R
  gemm_tp<320, 0, false><<<512, 256, 0, stream>>>(
      P, nullptr, nullptr, Wh, P, N_BONDS, nTilesB);
  agg_kernel<<<gagg, 256, 0, stream>>>(P, a2b, R);

  // 3) FUSED round 2: Z2 = relu(nei1[b2a] - Z1[rev]) @ Wh^T (in-place P)
  gemm_tpf<<<512, 256, 0, stream>>>(P, R, b2a, Wh, P, nTilesB);

  // 4) nei2 -> R; msg2 = combineH(nei2, Z2) -> P in-place
  agg_kernel<<<gagg, 256, 0, stream>>>(P, a2b, R);
  combineH_kernel<<<gpar, 256, 0, stream>>>(R, P, b2a, P);

  // 5) amsg -> R; hidden = relu([fa_bf|amsg] @ Wo^T + b_o) -> R in-place
  agg_kernel<<<gagg, 256, 0, stream>>>(P, a2b, R);
  gemm_tpo<<<512, 256, 0, stream>>>(fa_bf, R, Wo, b_o, R, N_ATOMS, nTilesA);

  // 6) readout
  readout_kernel<<<(N_MOLS * (NPAD / 8) + 255) / 256, 256, 0, stream>>>(R, a_scope, out);
}

// Round 21
// 640.852 us; speedup vs baseline: 1.2001x; 1.2001x over previous
//
#include <hip/hip_runtime.h>
#include <stdint.h>

#define N_ATOMS   100000
#define N_BONDS   200000
#define N_MOLS    4000
#define MAX_NB    6
#define ATOM_FDIM 133
#define BOND_FDIM 14
#define HIDDEN    300
#define NPAD      320

typedef __attribute__((ext_vector_type(8))) short          bf16x8;
typedef __attribute__((ext_vector_type(8))) unsigned short u16x8;
typedef __attribute__((ext_vector_type(4))) float          f32x4;
typedef __attribute__((ext_vector_type(4))) unsigned int   u32x4;

static __device__ __forceinline__ float u2f(unsigned int u) {
  union { unsigned int u; float f; } v; v.u = u; return v.f;
}
static __device__ __forceinline__ unsigned int f2u(float f) {
  union { float f; unsigned int u; } v; v.f = f; return v.u;
}
static __device__ __forceinline__ float bflo(unsigned int u) { return u2f(u << 16); }
static __device__ __forceinline__ float bfhi(unsigned int u) { return u2f(u & 0xffff0000u); }
static __device__ __forceinline__ unsigned short f2bf_rn(float f) {
  unsigned int u = f2u(f);
  return (unsigned short)((u + 0x7fffu + ((u >> 16) & 1u)) >> 16);
}
static __device__ __forceinline__ unsigned int pack_rn(float lo, float hi) {
  return ((unsigned int)f2bf_rn(hi) << 16) | f2bf_rn(lo);
}

// ---- input pad/convert: f32[N][K] -> bf16[N][KP], zero pad ----
__global__ __launch_bounds__(256) void convin_kernel(
    const float* __restrict__ w, unsigned short* __restrict__ o, int N, int K, int KP) {
  size_t total = (size_t)N * KP;
  for (size_t idx = (size_t)blockIdx.x * 256 + threadIdx.x; idx < total; idx += (size_t)gridDim.x * 256) {
    int n = (int)(idx / KP), k = (int)(idx - (size_t)n * KP);
    float v = (k < K) ? w[(size_t)n * K + k] : 0.f;
    o[idx] = f2bf_rn(v);
  }
}

// ---- weight pad/convert, generic 2-segment remap: o[NPAD][KP] bf16 ----
__global__ __launch_bounds__(256) void convw_kernel(
    const float* __restrict__ w, unsigned short* __restrict__ o,
    int Ksrc, int seg1, int src2off, int seg2dst, int seg2len, int KP) {
  int total = NPAD * KP;
  for (int idx = blockIdx.x * 256 + threadIdx.x; idx < total; idx += gridDim.x * 256) {
    int n = idx / KP, k = idx - n * KP;
    int src = -1;
    if (k < seg1) src = k;
    else if (k >= seg2dst && k < seg2dst + seg2len) src = src2off + (k - seg2dst);
    float v = (n < HIDDEN && src >= 0) ? w[(size_t)n * Ksrc + src] : 0.f;
    o[idx] = f2bf_rn(v);
  }
}

// ---- tile-pipelined MFMA GEMM with global_load_lds staging (r11-proven) ----
template<int KP, int SEG, bool RELU>
__global__ __launch_bounds__(256) void gemm_tp(
    const unsigned short* S1, const unsigned short* __restrict__ S2,
    const int* __restrict__ gmap, const unsigned short* __restrict__ W,
    unsigned short* out, int M, int nTiles) {
  constexpr int CHUNKS = KP / 8;
  constexpr int NST    = KP / 32;
  __shared__ __align__(16) unsigned short As[2 * 64 * KP];

  const int tid  = threadIdx.x;
  const int lane = tid & 63;
  const int wv   = tid >> 6;
  const int ar   = lane & 15, kq = lane >> 4;
  const int nbase = wv * 80;
  const unsigned short* Wl = W + (size_t)(nbase + ar) * KP + kq * 8;

  auto rowof = [&](int tile) { int r = tile * 64 + lane; return (r < M) ? r : (M - 1); };

  auto stage = [&](int buf, int drow, int srow) {
    char* base = (char*)As + (size_t)buf * (64 * KP * 2);
#pragma unroll
    for (int cs = wv; cs < CHUNKS; cs += 4) {
      const unsigned short* src;
      if (SEG == 0) src = S1 + (size_t)drow * KP + cs * 8;
      else src = (cs < 20) ? (S1 + (size_t)srow * 160 + cs * 8)
                           : (S2 + (size_t)drow * 32 + (cs - 20) * 8);
      __builtin_amdgcn_global_load_lds(
          (const __attribute__((address_space(1))) void*)src,
          (__attribute__((address_space(3))) void*)(base + (size_t)cs * 1024), 16, 0, 0);
    }
  };

  f32x4 acc[4][5];

  auto compute = [&](int buf) {
    const char* base = (const char*)As + (size_t)buf * (64 * KP * 2);
    bf16x8 bnxt[5];
#pragma unroll
    for (int nf = 0; nf < 5; nf++) bnxt[nf] = *(const bf16x8*)(Wl + (size_t)nf * 16 * KP);
#pragma unroll
    for (int ks = 0; ks < NST; ks++) {
      bf16x8 bcur[5];
#pragma unroll
      for (int nf = 0; nf < 5; nf++) bcur[nf] = bnxt[nf];
      if (ks + 1 < NST) {
#pragma unroll
        for (int nf = 0; nf < 5; nf++)
          bnxt[nf] = *(const bf16x8*)(Wl + (size_t)nf * 16 * KP + (ks + 1) * 32);
      }
      bf16x8 af[4];
#pragma unroll
      for (int m = 0; m < 4; m++)
        af[m] = *(const bf16x8*)(base + (size_t)((ks * 4 + kq) * 64 + m * 16 + ar) * 16);
#pragma unroll
      for (int nf = 0; nf < 5; nf++)
#pragma unroll
        for (int m = 0; m < 4; m++)
          acc[m][nf] = __builtin_amdgcn_mfma_f32_16x16x32_bf16(af[m], bcur[nf], acc[m][nf], 0, 0, 0);
    }
  };

  auto storeC = [&](int tile) {
#pragma unroll
    for (int m = 0; m < 4; m++)
#pragma unroll
      for (int rr = 0; rr < 4; rr++) {
        int orow = tile * 64 + m * 16 + kq * 4 + rr;
        if (orow >= M) continue;
#pragma unroll
        for (int nf = 0; nf < 5; nf++) {
          float v = acc[m][nf][rr];
          if (RELU) v = v > 0.f ? v : 0.f;
          out[(size_t)orow * NPAD + nbase + nf * 16 + ar] = f2bf_rn(v);
        }
      }
  };

  int t = blockIdx.x;
  if (t >= nTiles) return;
  {
    int srow0 = (SEG == 1) ? gmap[rowof(t)] : 0;
    stage(0, rowof(t), srow0);
  }
  int tn = t + gridDim.x;
  int g_n = (SEG == 1 && tn < nTiles) ? gmap[rowof(tn)] : 0;
  __syncthreads();

  int cur = 0;
  while (t < nTiles) {
    const int nxt = t + gridDim.x;
    if (nxt < nTiles) stage(cur ^ 1, rowof(nxt), g_n);
    const int t2 = nxt + gridDim.x;
    int g_n2 = (SEG == 1 && t2 < nTiles) ? gmap[rowof(t2)] : 0;
#pragma unroll
    for (int m = 0; m < 4; m++)
#pragma unroll
      for (int n = 0; n < 5; n++) acc[m][n] = (f32x4){0.f, 0.f, 0.f, 0.f};
    compute(cur);
    __syncthreads();
    storeC(t);
    cur ^= 1; t = nxt; g_n = g_n2;
  }
}

// ---- fused combine+GEMM, K-chunked unit pipeline (r18-proven) ----
__global__ __launch_bounds__(256) void gemm_tpf(
    const unsigned short* Z, const unsigned short* __restrict__ Nei,
    const int* __restrict__ b2a, const unsigned short* __restrict__ W,
    unsigned short* out, int nTiles) {
  constexpr int KP = 320, BK = 160, NCH = 2, NSTC = 5, NREG = 5;
  __shared__ __align__(16) unsigned short As[2 * 64 * BK];   // 40 KB

  const int tid  = threadIdx.x;
  const int lane = tid & 63;
  const int wv   = tid >> 6;
  const int ar   = lane & 15, kq = lane >> 4;
  const int nbase = wv * 80;
  const unsigned short* Wl = W + (size_t)(nbase + ar) * KP + kq * 8;

  u32x4 nei4[NREG], z4[NREG];

  auto loadreg = [&](int tile, int chunk) {
    const int row = tile * 64 + lane;          // N_BONDS is 64-aligned
    const int g   = b2a[row];
    const int rev = row ^ 1;
    const int kb  = chunk * BK;
#pragma unroll
    for (int i = 0; i < NREG; i++) {
      const int cs = i * 4 + wv;               // 0..19
      nei4[i] = *(const u32x4*)(Nei + (size_t)g * NPAD + kb + cs * 8);
      z4[i]   = *(const u32x4*)(Z + (size_t)rev * NPAD + kb + cs * 8);
    }
  };

  auto writestage = [&](int buf) {
    char* base = (char*)As + (size_t)buf * (64 * BK * 2);
#pragma unroll
    for (int i = 0; i < NREG; i++) {
      const int cs = i * 4 + wv;
      u32x4 o;
#pragma unroll
      for (int t4 = 0; t4 < 4; t4++) {
        float lo = bflo(nei4[i][t4]) - bflo(z4[i][t4]);
        float hi = bfhi(nei4[i][t4]) - bfhi(z4[i][t4]);
        lo = lo > 0.f ? lo : 0.f; hi = hi > 0.f ? hi : 0.f;
        o[t4] = pack_rn(lo, hi);
      }
      *(u32x4*)(base + (size_t)(cs * 64 + lane) * 16) = o;
    }
  };

  f32x4 acc[4][5];

  auto compute = [&](int buf, int chunk) {
    const char* base = (const char*)As + (size_t)buf * (64 * BK * 2);
    const int kb = chunk * BK;
#pragma unroll
    for (int ks = 0; ks < NSTC; ks++) {
      bf16x8 af[4];
#pragma unroll
      for (int m = 0; m < 4; m++)
        af[m] = *(const bf16x8*)(base + (size_t)((ks * 4 + kq) * 64 + m * 16 + ar) * 16);
#pragma unroll
      for (int nf = 0; nf < 5; nf++) {
        bf16x8 bfr = *(const bf16x8*)(Wl + (size_t)nf * 16 * KP + kb + ks * 32);
#pragma unroll
        for (int m = 0; m < 4; m++)
          acc[m][nf] = __builtin_amdgcn_mfma_f32_16x16x32_bf16(af[m], bfr, acc[m][nf], 0, 0, 0);
      }
    }
  };

  auto storeC = [&](int tile) {
#pragma unroll
    for (int m = 0; m < 4; m++)
#pragma unroll
      for (int rr = 0; rr < 4; rr++) {
        int orow = tile * 64 + m * 16 + kq * 4 + rr;
#pragma unroll
        for (int nf = 0; nf < 5; nf++)
          out[(size_t)orow * NPAD + nbase + nf * 16 + ar] = f2bf_rn(acc[m][nf][rr]);
      }
  };

  int t = blockIdx.x;
  if (t >= nTiles) return;
  loadreg(t, 0);
  writestage(0);
  __syncthreads();

  int cur = 0;
  while (t < nTiles) {
#pragma unroll
    for (int m = 0; m < 4; m++)
#pragma unroll
      for (int n = 0; n < 5; n++) acc[m][n] = (f32x4){0.f, 0.f, 0.f, 0.f};
#pragma unroll
    for (int c = 0; c < NCH; c++) {
      int nt = t, nc = c + 1;
      if (nc == NCH) { nt = t + gridDim.x; nc = 0; }
      const bool valid = nt < nTiles;
      if (valid) loadreg(nt, nc);       // issue early: hides under compute
      compute(cur, c);
      if (valid) writestage(cur ^ 1);   // waits loads; ds_write late
      __syncthreads();
      cur ^= 1;
    }
    storeC(t);
    t += gridDim.x;
  }
}

// ---- final KP=480 GEMM: K-chunked tile pipeline (r19-measured-best) ----
__global__ __launch_bounds__(256) void gemm_tpo(
    const unsigned short* __restrict__ fa_bf, const unsigned short* Ab,
    const unsigned short* __restrict__ W, const float* __restrict__ bias,
    unsigned short* out, int M, int nTiles) {
  constexpr int KP = 480, BK = 160, NCH = 3, NSTC = 5, CHG = 20;
  __shared__ __align__(16) unsigned short As[2 * 64 * BK];   // 40 KB

  const int tid  = threadIdx.x;
  const int lane = tid & 63;
  const int wv   = tid >> 6;
  const int ar   = lane & 15, kq = lane >> 4;
  const int nbase = wv * 80;
  const unsigned short* Wl = W + (size_t)(nbase + ar) * KP + kq * 8;

  auto stage = [&](int buf, int tile, int chunk) {
    char* base = (char*)As + (size_t)buf * (64 * BK * 2);
    int r = tile * 64 + lane; if (r >= M) r = M - 1;
#pragma unroll
    for (int cl = wv; cl < CHG; cl += 4) {
      const int ae = (chunk * CHG + cl) * 8;
      const unsigned short* src = (ae < 160)
          ? (fa_bf + (size_t)r * 160 + ae)
          : (Ab + (size_t)r * NPAD + (ae - 160));
      __builtin_amdgcn_global_load_lds(
          (const __attribute__((address_space(1))) void*)src,
          (__attribute__((address_space(3))) void*)(base + (size_t)cl * 1024), 16, 0, 0);
    }
  };

  f32x4 acc[4][5];

  auto compute = [&](int buf, int chunk) {
    const char* base = (const char*)As + (size_t)buf * (64 * BK * 2);
    const int kb = chunk * BK;
#pragma unroll
    for (int ks = 0; ks < NSTC; ks++) {
      bf16x8 af[4];
#pragma unroll
      for (int m = 0; m < 4; m++)
        af[m] = *(const bf16x8*)(base + (size_t)((ks * 4 + kq) * 64 + m * 16 + ar) * 16);
#pragma unroll
      for (int nf = 0; nf < 5; nf++) {
        bf16x8 bfr = *(const bf16x8*)(Wl + (size_t)nf * 16 * KP + kb + ks * 32);
#pragma unroll
        for (int m = 0; m < 4; m++)
          acc[m][nf] = __builtin_amdgcn_mfma_f32_16x16x32_bf16(af[m], bfr, acc[m][nf], 0, 0, 0);
      }
    }
  };

  auto storeC = [&](int tile) {
#pragma unroll
    for (int m = 0; m < 4; m++)
#pragma unroll
      for (int rr = 0; rr < 4; rr++) {
        int orow = tile * 64 + m * 16 + kq * 4 + rr;
        if (orow >= M) continue;
#pragma unroll
        for (int nf = 0; nf < 5; nf++) {
          int ocol = nbase + nf * 16 + ar;
          float v = acc[m][nf][rr];
          v += (ocol < HIDDEN) ? bias[ocol] : 0.f;
          v = v > 0.f ? v : 0.f;
          out[(size_t)orow * NPAD + ocol] = f2bf_rn(v);
        }
      }
  };

  int t = blockIdx.x;
  if (t >= nTiles) return;
  stage(0, t, 0);
  __syncthreads();

  int cur = 0;
  while (t < nTiles) {
#pragma unroll
    for (int m = 0; m < 4; m++)
#pragma unroll
      for (int n = 0; n < 5; n++) acc[m][n] = (f32x4){0.f, 0.f, 0.f, 0.f};
#pragma unroll
    for (int c = 0; c < NCH; c++) {
      int nt = t, nc = c + 1;
      if (nc == NCH) { nt = t + gridDim.x; nc = 0; }
      if (nt < nTiles) stage(cur ^ 1, nt, nc);
      compute(cur, c);
      __syncthreads();
      cur ^= 1;
    }
    storeC(t);
    t += gridDim.x;
  }
}

// ---- neighbor aggregate: dst[a][:] = sum_j src[a2b[a][j]][:] ----
__global__ __launch_bounds__(256) void agg_kernel(
    const unsigned short* __restrict__ src, const int* __restrict__ a2b,
    unsigned short* __restrict__ dst) {
  const int TPA = NPAD / 16;  // 20
  int idx = blockIdx.x * 256 + threadIdx.x;
  if (idx >= N_ATOMS * TPA) return;
  int a  = idx / TPA;
  int kc = (idx - a * TPA) * 16;
  int bidx[MAX_NB];
#pragma unroll
  for (int j = 0; j < MAX_NB; j++) bidx[j] = a2b[a * MAX_NB + j];
  float slo[8], shi[8];
#pragma unroll
  for (int t = 0; t < 8; t++) { slo[t] = 0.f; shi[t] = 0.f; }
#pragma unroll
  for (int j = 0; j < MAX_NB; j++) {
    const u32x4* p = (const u32x4*)(src + (size_t)bidx[j] * NPAD + kc);
    u32x4 v0 = p[0], v1 = p[1];
#pragma unroll
    for (int t = 0; t < 4; t++) {
      slo[t]     += bflo(v0[t]); shi[t]     += bfhi(v0[t]);
      slo[4 + t] += bflo(v1[t]); shi[4 + t] += bfhi(v1[t]);
    }
  }
  u32x4 o0, o1;
#pragma unroll
  for (int t = 0; t < 4; t++) { o0[t] = pack_rn(slo[t], shi[t]); o1[t] = pack_rn(slo[4 + t], shi[4 + t]); }
  u32x4* qp = (u32x4*)(dst + (size_t)a * NPAD + kc);
  qp[0] = o0; qp[1] = o1;
}

// ---- pairwise: msg[b] = relu(neiZ[b2a[b]] - Zh[b^1]), in-place over Zh ----
__global__ __launch_bounds__(256) void combineH_kernel(
    const unsigned short* __restrict__ neiZ, const unsigned short* Zh,
    const int* __restrict__ b2a, unsigned short* msg) {
  const int TPB = NPAD / 16;  // 20
  const int NPAIR = N_BONDS / 2;
  int idx = blockIdx.x * 256 + threadIdx.x;
  if (idx >= NPAIR * TPB) return;
  int p  = idx / TPB;
  int kc = (idx - p * TPB) * 16;
  int b0i = 2 * p, b1i = 2 * p + 1;
  int g0 = b2a[b0i], g1 = b2a[b1i];
  const u32x4* pn0 = (const u32x4*)(neiZ + (size_t)g0 * NPAD + kc);
  const u32x4* pn1 = (const u32x4*)(neiZ + (size_t)g1 * NPAD + kc);
  const u32x4* pz0 = (const u32x4*)(Zh + (size_t)b1i * NPAD + kc);
  const u32x4* pz1 = (const u32x4*)(Zh + (size_t)b0i * NPAD + kc);
  u32x4 n00 = pn0[0], n01 = pn0[1], n10 = pn1[0], n11 = pn1[1];
  u32x4 z00 = pz0[0], z01 = pz0[1], z10 = pz1[0], z11 = pz1[1];
  u32x4 o00, o01, o10, o11;
#pragma unroll
  for (int t = 0; t < 4; t++) {
    float a, c;
    a = bflo(n00[t]) - bflo(z00[t]); c = bfhi(n00[t]) - bfhi(z00[t]);
    o00[t] = pack_rn(a > 0.f ? a : 0.f, c > 0.f ? c : 0.f);
    a = bflo(n01[t]) - bflo(z01[t]); c = bfhi(n01[t]) - bfhi(z01[t]);
    o01[t] = pack_rn(a > 0.f ? a : 0.f, c > 0.f ? c : 0.f);
    a = bflo(n10[t]) - bflo(z10[t]); c = bfhi(n10[t]) - bfhi(z10[t]);
    o10[t] = pack_rn(a > 0.f ? a : 0.f, c > 0.f ? c : 0.f);
    a = bflo(n11[t]) - bflo(z11[t]); c = bfhi(n11[t]) - bfhi(z11[t]);
    o11[t] = pack_rn(a > 0.f ? a : 0.f, c > 0.f ? c : 0.f);
  }
  u32x4* q0 = (u32x4*)(msg + (size_t)b0i * NPAD + kc);
  u32x4* q1 = (u32x4*)(msg + (size_t)b1i * NPAD + kc);
  q0[0] = o00; q0[1] = o01; q1[0] = o10; q1[1] = o11;
}

// ---- per-molecule mean readout ----
__global__ __launch_bounds__(256) void readout_kernel(
    const unsigned short* __restrict__ hidden, const int* __restrict__ a_scope,
    float* __restrict__ out) {
  const int TPM = NPAD / 8;  // 40
  int idx = blockIdx.x * 256 + threadIdx.x;
  if (idx >= N_MOLS * TPM) return;
  int m = idx / TPM;
  int c = (idx - m * TPM) * 8;
  int start = a_scope[m * 2], size = a_scope[m * 2 + 1];
  float s[8];
#pragma unroll
  for (int t = 0; t < 8; t++) s[t] = 0.f;
  for (int i = 0; i < size; i++) {
    const u32x4 v = *(const u32x4*)(hidden + (size_t)(start + i) * NPAD + c);
#pragma unroll
    for (int t = 0; t < 4; t++) { s[2 * t] += bflo(v[t]); s[2 * t + 1] += bfhi(v[t]); }
  }
  float inv = (size > 0) ? 1.f / (float)size : 0.f;
#pragma unroll
  for (int t = 0; t < 8; t++) {
    int col = c + t;
    if (col < HIDDEN) out[(size_t)m * HIDDEN + col] = s[t] * inv;
  }
}

extern "C" void kernel_launch(void* const* d_in, const int* in_sizes, int n_in,
                              void* d_out, int out_size, void* d_ws, size_t ws_size,
                              hipStream_t stream) {
  const float* f_atoms = (const float*)d_in[0];
  const float* f_bonds = (const float*)d_in[1];
  const int*   a2b     = (const int*)d_in[2];
  const int*   b2a     = (const int*)d_in[3];
  // d_in[4] = b2revb == b^1 (constant from setup), folded into combine paths
  const int*   a_scope = (const int*)d_in[5];
  const float* W_i     = (const float*)d_in[6];
  const float* W_h     = (const float*)d_in[7];
  const float* W_o     = (const float*)d_in[8];
  const float* b_o     = (const float*)d_in[9];
  float* out = (float*)d_out;

  // ---- workspace: P 128 + R 64 + fa_bf 32 + fb_bf 12.8 + W ~0.7 = 237.5 MB ----
  char* ws = (char*)d_ws;
  size_t off = 0;
  auto alloc = [&](size_t bytes) { size_t o = off; off += (bytes + 255) & ~(size_t)255; return o; };
  unsigned short* P     = (unsigned short*)(ws + alloc((size_t)N_BONDS * NPAD * 2)); // msg/Z
  unsigned short* R     = (unsigned short*)(ws + alloc((size_t)N_ATOMS * NPAD * 2)); // nei/amsg/hidden
  unsigned short* fa_bf = (unsigned short*)(ws + alloc((size_t)N_ATOMS * 160 * 2));
  unsigned short* fb_bf = (unsigned short*)(ws + alloc((size_t)N_BONDS * 32 * 2));
  unsigned short* WiAB  = (unsigned short*)(ws + alloc((size_t)NPAD * 192 * 2));
  unsigned short* Wh    = (unsigned short*)(ws + alloc((size_t)NPAD * 320 * 2));
  unsigned short* Wo    = (unsigned short*)(ws + alloc((size_t)NPAD * 480 * 2));

  convin_kernel<<<2048, 256, 0, stream>>>(f_atoms, fa_bf, N_ATOMS, ATOM_FDIM, 160);
  convin_kernel<<<2048, 256, 0, stream>>>(f_bonds, fb_bf, N_BONDS, BOND_FDIM, 32);
  convw_kernel<<<(NPAD * 192 + 255) / 256, 256, 0, stream>>>(W_i, WiAB, 147, 133, 133, 160, 14, 192);
  convw_kernel<<<(NPAD * 320 + 255) / 256, 256, 0, stream>>>(W_h, Wh, 300, 300, 0, 0, 0, 320);
  convw_kernel<<<(NPAD * 480 + 255) / 256, 256, 0, stream>>>(W_o, Wo, 433, 133, 133, 160, 300, 480);

  const int nTilesB = N_BONDS / 64;           // 3125
  const int nTilesA = (N_ATOMS + 63) / 64;    // 1563
  const int gagg = (N_ATOMS * (NPAD / 16) + 255) / 256;
  const int gpar = ((N_BONDS / 2) * (NPAD / 16) + 255) / 256;

  // 1) L1: P = msg0 = relu([fa_bf[b2a]|fb_bf] @ WiAB^T)
  gemm_tp<192, 1, true><<<768, 256, 0, stream>>>(
      fa_bf, fb_bf, b2a, WiAB, P, N_BONDS, nTilesB);

  // 2) Z1 = msg0 @ Wh^T (in-place P); nei1 -> R
  gemm_tp<320, 0, false><<<512, 256, 0, stream>>>(
      P, nullptr, nullptr, Wh, P, N_BONDS, nTilesB);
  agg_kernel<<<gagg, 256, 0, stream>>>(P, a2b, R);

  // 3) FUSED round 2: Z2 = relu(nei1[b2a] - Z1[rev]) @ Wh^T (in-place P)
  gemm_tpf<<<512, 256, 0, stream>>>(P, R, b2a, Wh, P, nTilesB);

  // 4) nei2 -> R; msg2 = combineH(nei2, Z2) -> P in-place
  agg_kernel<<<gagg, 256, 0, stream>>>(P, a2b, R);
  combineH_kernel<<<gpar, 256, 0, stream>>>(R, P, b2a, P);

  // 5) amsg -> R; hidden = relu([fa_bf|amsg] @ Wo^T + b_o) -> R in-place
  agg_kernel<<<gagg, 256, 0, stream>>>(P, a2b, R);
  gemm_tpo<<<512, 256, 0, stream>>>(fa_bf, R, Wo, b_o, R, N_ATOMS, nTilesA);

  // 6) readout
  readout_kernel<<<(N_MOLS * (NPAD / 8) + 255) / 256, 256, 0, stream>>>(R, a_scope, out);
}